// Round 1
// baseline (1022.257 us; speedup 1.0000x reference)
//
#include <hip/hip_runtime.h>

typedef __bf16 bf16;
typedef __bf16 bf16x4 __attribute__((ext_vector_type(4)));
typedef __bf16 bf16x8 __attribute__((ext_vector_type(8)));
typedef float f32x4 __attribute__((ext_vector_type(4)));

#define DIMC 384
#define NHEADS 12
#define NTOK 49
#define NWINB 4096
#define MROWS (NWINB*NTOK)   // 200704

// ---------------- convert f32 -> bf16 (vectorized) ----------------
__global__ __launch_bounds__(256) void k_convert(const float4* __restrict__ in,
                                                 bf16x4* __restrict__ out, int n4) {
  int stride = gridDim.x * blockDim.x;
  for (int i = blockIdx.x * blockDim.x + threadIdx.x; i < n4; i += stride) {
    float4 v = in[i];
    bf16x4 o;
    o[0] = (bf16)v.x; o[1] = (bf16)v.y; o[2] = (bf16)v.z; o[3] = (bf16)v.w;
    out[i] = o;
  }
}

// ---------------- bias gather: biasf[h][m][n] = table[rel[m*49+n]*12 + h] ----------------
__global__ __launch_bounds__(256) void k_bias(const float* __restrict__ table,
                                              const int* __restrict__ rel,
                                              float* __restrict__ bout) {
  int i = blockIdx.x * 256 + threadIdx.x;
  if (i < NHEADS * NTOK * NTOK) {
    int h = i / (NTOK * NTOK);
    int ij = i - h * (NTOK * NTOK);
    bout[i] = table[rel[ij] * NHEADS + h];
  }
}

// ---------------- GEMM: C = A(M,K) * Bw(N,K)^T, bf16 in, f32 acc ----------------
// MODE 0: QKV (N=1152), scatter q/k/v bf16.  MODE 1: proj (N=384), f32 out + bias.
template <int MODE>
__global__ __launch_bounds__(256) void k_gemm(const bf16* __restrict__ A,
                                              const bf16* __restrict__ Bw,
                                              const float* __restrict__ bias,
                                              bf16* __restrict__ oQ, bf16* __restrict__ oK,
                                              bf16* __restrict__ oV, float* __restrict__ oP) {
  constexpr int LDT = 72;   // pad 64 -> 72 bf16: 144B row stride, 2-way-max LDS conflicts
  __shared__ __align__(16) bf16 lA[128 * LDT];
  __shared__ __align__(16) bf16 lB[128 * LDT];
  const int t = threadIdx.x;
  const int l = t & 63;
  const int wv = t >> 6;
  const int wr = wv >> 1, wc = wv & 1;   // 2x2 waves, 64x64 each
  const int m0 = blockIdx.x * 128;
  const int n0 = blockIdx.y * 128;
  const int lr = l & 15, lg = l >> 4;

  f32x4 acc[4][4] = {};

  for (int k0 = 0; k0 < DIMC; k0 += 64) {
    __syncthreads();
#pragma unroll
    for (int i = 0; i < 4; ++i) {     // stage 128x64 A and B tiles
      int idx = i * 256 + t;          // 0..1023
      int row = idx >> 3;
      int col = (idx & 7) * 8;
      *reinterpret_cast<bf16x8*>(&lA[row * LDT + col]) =
          *reinterpret_cast<const bf16x8*>(&A[(m0 + row) * DIMC + k0 + col]);
      *reinterpret_cast<bf16x8*>(&lB[row * LDT + col]) =
          *reinterpret_cast<const bf16x8*>(&Bw[(n0 + row) * DIMC + k0 + col]);
    }
    __syncthreads();
#pragma unroll
    for (int kk = 0; kk < 64; kk += 32) {
      bf16x8 af[4], bfv[4];
#pragma unroll
      for (int f = 0; f < 4; ++f)
        af[f] = *reinterpret_cast<const bf16x8*>(&lA[(wr * 64 + f * 16 + lr) * LDT + kk + lg * 8]);
#pragma unroll
      for (int f = 0; f < 4; ++f)
        bfv[f] = *reinterpret_cast<const bf16x8*>(&lB[(wc * 64 + f * 16 + lr) * LDT + kk + lg * 8]);
#pragma unroll
      for (int fm = 0; fm < 4; ++fm)
#pragma unroll
        for (int fn = 0; fn < 4; ++fn)
          acc[fm][fn] = __builtin_amdgcn_mfma_f32_16x16x32_bf16(af[fm], bfv[fn], acc[fm][fn], 0, 0, 0);
    }
  }

  // epilogue: C/D frag mapping col = lane&15, row = (lane>>4)*4 + r  [m89-verified]
#pragma unroll
  for (int fm = 0; fm < 4; ++fm) {
#pragma unroll
    for (int fn = 0; fn < 4; ++fn) {
      int c = n0 + wc * 64 + fn * 16 + lr;
      float bc = bias[c];
#pragma unroll
      for (int r = 0; r < 4; ++r) {
        int m = m0 + wr * 64 + fm * 16 + lg * 4 + r;
        float v = acc[fm][fn][r] + bc;
        if (MODE == 0) {
          // qkv[b, n, which, h, d]; write q/k/v as (b*12+h, n, d) bf16
          int b = m / 49, n = m - b * 49;
          int which = c / 384;
          int rem = c - which * 384;
          int h = rem >> 5, d = rem & 31;
          bf16* dst = which == 0 ? oQ : (which == 1 ? oK : oV);
          dst[((b * 12 + h) * 49 + n) * 32 + d] = (bf16)v;
        } else {
          oP[m * 384 + c] = v;
        }
      }
    }
  }
}

// ---------------- fused window attention: one wave per (b,h) ----------------
__global__ __launch_bounds__(256) void k_attn(const bf16* __restrict__ Q,
                                              const bf16* __restrict__ Kt,
                                              const bf16* __restrict__ V,
                                              const float* __restrict__ biasf,
                                              const float* __restrict__ maskf,
                                              bf16* __restrict__ H) {
  __shared__ __align__(16) bf16 Pl[4][64 * 72];
  __shared__ __align__(16) bf16 Vl[4][32 * 72];
  const int t = threadIdx.x, l = t & 63, wv = t >> 6;
  const int p = blockIdx.x * 4 + wv;        // (b*12 + h)
  const int b = p / 12, h = p - b * 12;
  const int w = b & 63;                     // mask index = b % 64
  const int base = p * (49 * 32);
  const int lr = l & 15, lg = l >> 4;
  bf16* pl = Pl[wv];
  bf16* vl = Vl[wv];

  // zero V pad keys 49..64 (so padded P cols multiply finite zeros)
  for (int i = l; i < 512; i += 64) {
    int dd = i >> 4, key = 49 + (i & 15);
    vl[dd * 72 + key] = (bf16)0.f;
  }
  // stage V transposed into LDS: vl[d][key]
  for (int i = l; i < 392; i += 64) {       // 49 keys * 8 chunks of 4 d
    int key = i >> 3, dc = (i & 7) * 4;
    bf16x4 vv = *reinterpret_cast<const bf16x4*>(&V[base + key * 32 + dc]);
#pragma unroll
    for (int j = 0; j < 4; ++j) vl[(dc + j) * 72 + key] = vv[j];
  }

  // QK^T via MFMA; rows clamped to 48 (keeps loads in-bounds, garbage rows discarded)
  bf16x8 qf[4], kf[4];
#pragma unroll
  for (int f = 0; f < 4; ++f) {
    int mr = f * 16 + lr; if (mr > 48) mr = 48;
    qf[f] = *reinterpret_cast<const bf16x8*>(&Q[base + mr * 32 + lg * 8]);
    kf[f] = *reinterpret_cast<const bf16x8*>(&Kt[base + mr * 32 + lg * 8]);
  }
  f32x4 s[4][4] = {};
#pragma unroll
  for (int fm = 0; fm < 4; ++fm)
#pragma unroll
    for (int fn = 0; fn < 4; ++fn)
      s[fm][fn] = __builtin_amdgcn_mfma_f32_16x16x32_bf16(qf[fm], kf[fn], s[fm][fn], 0, 0, 0);

  const float scale = 0.17677669529663689f;   // 32^-0.5
  const float* bh_b = biasf + h * 2401;
  const float* bw_m = maskf + w * 2401;
#pragma unroll
  for (int fm = 0; fm < 4; ++fm) {
#pragma unroll
    for (int r = 0; r < 4; ++r) {
      int m = fm * 16 + lg * 4 + r;
      int mc = m > 48 ? 48 : m;
      float vmax = -1e30f;
#pragma unroll
      for (int fn = 0; fn < 4; ++fn) {
        int cc = fn * 16 + lr;
        float sv;
        if (cc < 49) sv = s[fm][fn][r] * scale + bh_b[mc * 49 + cc] + bw_m[mc * 49 + cc];
        else sv = -1e30f;
        s[fm][fn][r] = sv;
        vmax = fmaxf(vmax, sv);
      }
#pragma unroll
      for (int sh = 1; sh < 16; sh <<= 1) vmax = fmaxf(vmax, __shfl_xor(vmax, sh));
      float sum = 0.f;
#pragma unroll
      for (int fn = 0; fn < 4; ++fn) {
        float e = __expf(s[fm][fn][r] - vmax);
        s[fm][fn][r] = e;
        sum += e;
      }
#pragma unroll
      for (int sh = 1; sh < 16; sh <<= 1) sum += __shfl_xor(sum, sh);
      float inv = 1.f / sum;
#pragma unroll
      for (int fn = 0; fn < 4; ++fn) {
        int cc = fn * 16 + lr;
        pl[m * 72 + cc] = (bf16)(cc < 49 ? s[fm][fn][r] * inv : 0.f);
      }
    }
  }
  __syncthreads();

  // PV: O(49x32) = P(49x64) * V(64x32), padded keys contribute 0
  f32x4 o[4][2] = {};
#pragma unroll
  for (int kk = 0; kk < 64; kk += 32) {
    bf16x8 pf[4], vf[2];
#pragma unroll
    for (int f = 0; f < 4; ++f)
      pf[f] = *reinterpret_cast<const bf16x8*>(&pl[(f * 16 + lr) * 72 + kk + lg * 8]);
#pragma unroll
    for (int f = 0; f < 2; ++f)
      vf[f] = *reinterpret_cast<const bf16x8*>(&vl[(f * 16 + lr) * 72 + kk + lg * 8]);
#pragma unroll
    for (int fm = 0; fm < 4; ++fm)
#pragma unroll
      for (int fn = 0; fn < 2; ++fn)
        o[fm][fn] = __builtin_amdgcn_mfma_f32_16x16x32_bf16(pf[fm], vf[fn], o[fm][fn], 0, 0, 0);
  }
#pragma unroll
  for (int fm = 0; fm < 4; ++fm) {
#pragma unroll
    for (int fn = 0; fn < 2; ++fn) {
#pragma unroll
      for (int r = 0; r < 4; ++r) {
        int m = fm * 16 + lg * 4 + r;
        if (m < 49) {
          int d = fn * 16 + lr;
          H[(b * 49 + m) * 384 + h * 32 + d] = (bf16)o[fm][fn][r];
        }
      }
    }
  }
}

extern "C" void kernel_launch(void* const* d_in, const int* in_sizes, int n_in,
                              void* d_out, int out_size, void* d_ws, size_t ws_size,
                              hipStream_t stream) {
  const float* x     = (const float*)d_in[0];
  const float* mask  = (const float*)d_in[1];
  const float* qkvw  = (const float*)d_in[2];
  const float* qkvb  = (const float*)d_in[3];
  const float* btab  = (const float*)d_in[4];
  const float* projw = (const float*)d_in[5];
  const float* projb = (const float*)d_in[6];
  const int*   rel   = (const int*)d_in[7];
  float* out = (float*)d_out;

  const size_t NELEM = (size_t)MROWS * DIMC;  // 77,070,336
  char* ws = (char*)d_ws;
  // ws layout (bytes): xb/hidden [0, 154140672) | v [154140672, 308281344)
  //                    biasf [308281344, +115264) | wqkv | wproj   (~296 MB total)
  bf16*  xb    = (bf16*)ws;
  bf16*  vb    = (bf16*)(ws + 154140672);
  float* biasf = (float*)(ws + 308281344);
  bf16*  wqkv  = (bf16*)(ws + 308281344 + 115264);
  bf16*  wproj = (bf16*)(ws + 308281344 + 115264 + 884736);
  // q,k live in d_out as scratch (exactly 2 * 154,140,672 B); proj fully overwrites it
  bf16* qb = (bf16*)d_out;
  bf16* kb = qb + NELEM;

  k_convert<<<2048, 256, 0, stream>>>((const float4*)x, (bf16x4*)xb, (int)(NELEM / 4));
  k_convert<<<432, 256, 0, stream>>>((const float4*)qkvw, (bf16x4*)wqkv, 3 * DIMC * DIMC / 4);
  k_convert<<<144, 256, 0, stream>>>((const float4*)projw, (bf16x4*)wproj, DIMC * DIMC / 4);
  k_bias<<<(NHEADS * NTOK * NTOK + 255) / 256, 256, 0, stream>>>(btab, rel, biasf);

  k_gemm<0><<<dim3(MROWS / 128, 1152 / 128), 256, 0, stream>>>(xb, wqkv, qkvb, qb, kb, vb, nullptr);
  k_attn<<<(NWINB * NHEADS) / 4, 256, 0, stream>>>(qb, kb, vb, biasf, mask, xb);
  k_gemm<1><<<dim3(MROWS / 128, 384 / 128), 256, 0, stream>>>(xb, wproj, projb, nullptr, nullptr, nullptr, out);
}

// Round 2
// 851.603 us; speedup vs baseline: 1.2004x; 1.2004x over previous
//
#include <hip/hip_runtime.h>

typedef __bf16 bf16;
typedef __bf16 bf16x4 __attribute__((ext_vector_type(4)));
typedef __bf16 bf16x8 __attribute__((ext_vector_type(8)));
typedef float f32x4 __attribute__((ext_vector_type(4)));
typedef float f32x16 __attribute__((ext_vector_type(16)));
typedef int i32x2 __attribute__((ext_vector_type(2)));
typedef unsigned int u32;

#define DIMC 384
#define NHEADS 12
#define NTOK 49
#define NWINB 4096
#define MROWS (NWINB*NTOK)   // 200704

#define MFMA32(A,B,C) __builtin_amdgcn_mfma_f32_32x32x16_bf16(A,B,C,0,0,0)

// ---------------- convert f32 -> bf16 (vectorized) ----------------
__global__ __launch_bounds__(256) void k_convert(const float4* __restrict__ in,
                                                 bf16x4* __restrict__ out, int n4) {
  int stride = gridDim.x * blockDim.x;
  for (int i = blockIdx.x * blockDim.x + threadIdx.x; i < n4; i += stride) {
    float4 v = in[i];
    bf16x4 o;
    o[0] = (bf16)v.x; o[1] = (bf16)v.y; o[2] = (bf16)v.z; o[3] = (bf16)v.w;
    out[i] = o;
  }
}

// ---------------- transposed bias: biasT[h][key][q] = table[rel[q*49+key]*12 + h] ----------------
__global__ __launch_bounds__(256) void k_biasT(const float* __restrict__ table,
                                               const int* __restrict__ rel,
                                               float* __restrict__ outp) {
  int i = blockIdx.x * 256 + threadIdx.x;
  if (i < NHEADS * NTOK * NTOK) {
    int h = i / (NTOK * NTOK), r2 = i - h * (NTOK * NTOK);
    int key = r2 / NTOK, q = r2 - key * NTOK;
    outp[i] = table[rel[q * NTOK + key] * NHEADS + h];
  }
}

// ---------------- transposed mask: maskT[w][key][q] = mask[w][q][key] ----------------
__global__ __launch_bounds__(256) void k_maskT(const float* __restrict__ mask,
                                               float* __restrict__ outp) {
  int i = blockIdx.x * 256 + threadIdx.x;
  if (i < 64 * NTOK * NTOK) {
    int w = i / (NTOK * NTOK), r2 = i - w * (NTOK * NTOK);
    int key = r2 / NTOK, q = r2 - key * NTOK;
    outp[i] = mask[(w * NTOK + q) * NTOK + key];
  }
}

// ---------------- GEMM: C = A(M,K) * Bw(N,K)^T, bf16 in, f32 acc ----------------
// MODE 0: QKV (N=1152), scatter q/k/v bf16.  MODE 1: proj (N=384), f32 out + bias.
template <int MODE>
__global__ __launch_bounds__(256) void k_gemm(const bf16* __restrict__ A,
                                              const bf16* __restrict__ Bw,
                                              const float* __restrict__ bias,
                                              bf16* __restrict__ oQ, bf16* __restrict__ oK,
                                              bf16* __restrict__ oV, float* __restrict__ oP) {
  constexpr int LDT = 72;   // pad 64 -> 72 bf16: 144B row stride
  __shared__ __align__(16) bf16 lA[128 * LDT];
  __shared__ __align__(16) bf16 lB[128 * LDT];
  const int t = threadIdx.x;
  const int l = t & 63;
  const int wv = t >> 6;
  const int wr = wv >> 1, wc = wv & 1;   // 2x2 waves, 64x64 each
  const int m0 = blockIdx.x * 128;
  const int n0 = blockIdx.y * 128;
  const int lr = l & 15, lg = l >> 4;

  f32x4 acc[4][4] = {};

  for (int k0 = 0; k0 < DIMC; k0 += 64) {
    __syncthreads();
#pragma unroll
    for (int i = 0; i < 4; ++i) {     // stage 128x64 A and B tiles
      int idx = i * 256 + t;          // 0..1023
      int row = idx >> 3;
      int col = (idx & 7) * 8;
      *reinterpret_cast<bf16x8*>(&lA[row * LDT + col]) =
          *reinterpret_cast<const bf16x8*>(&A[(m0 + row) * DIMC + k0 + col]);
      *reinterpret_cast<bf16x8*>(&lB[row * LDT + col]) =
          *reinterpret_cast<const bf16x8*>(&Bw[(n0 + row) * DIMC + k0 + col]);
    }
    __syncthreads();
#pragma unroll
    for (int kk = 0; kk < 64; kk += 32) {
      bf16x8 af[4], bfv[4];
#pragma unroll
      for (int f = 0; f < 4; ++f)
        af[f] = *reinterpret_cast<const bf16x8*>(&lA[(wr * 64 + f * 16 + lr) * LDT + kk + lg * 8]);
#pragma unroll
      for (int f = 0; f < 4; ++f)
        bfv[f] = *reinterpret_cast<const bf16x8*>(&lB[(wc * 64 + f * 16 + lr) * LDT + kk + lg * 8]);
#pragma unroll
      for (int fm = 0; fm < 4; ++fm)
#pragma unroll
        for (int fn = 0; fn < 4; ++fn)
          acc[fm][fn] = __builtin_amdgcn_mfma_f32_16x16x32_bf16(af[fm], bfv[fn], acc[fm][fn], 0, 0, 0);
    }
  }

  // epilogue: C/D frag mapping col = lane&15, row = (lane>>4)*4 + r  [m89-verified]
#pragma unroll
  for (int fm = 0; fm < 4; ++fm) {
#pragma unroll
    for (int fn = 0; fn < 4; ++fn) {
      int c = n0 + wc * 64 + fn * 16 + lr;
      float bc = bias[c];
#pragma unroll
      for (int r = 0; r < 4; ++r) {
        int m = m0 + wr * 64 + fm * 16 + lg * 4 + r;
        float v = acc[fm][fn][r] + bc;
        if (MODE == 0) {
          int b = m / 49, n = m - b * 49;
          int which = c / 384;
          int rem = c - which * 384;
          int h = rem >> 5, d = rem & 31;
          bf16* dst = which == 0 ? oQ : (which == 1 ? oK : oV);
          dst[((b * 12 + h) * 49 + n) * 32 + d] = (bf16)v;
        } else {
          oP[m * 384 + c] = v;
        }
      }
    }
  }
}

// ---------------- fused window attention: one wave per (b,h), 32x32 MFMA ----------------
// Swapped QK^T: S = mfma(A=K, B=Q) -> lane holds S[key][q=c]; softmax lane-local + 1 shfl.
// P kept in registers; transposed to PV A-fragments via cvt_pk + permlane32_swap.
__global__ __launch_bounds__(256, 4) void k_attn(const bf16* __restrict__ Q,
                                                 const bf16* __restrict__ K,
                                                 const bf16* __restrict__ V,
                                                 const float* __restrict__ biasT,
                                                 const float* __restrict__ maskT,
                                                 bf16* __restrict__ H) {
  __shared__ __align__(16) bf16 Vl[4][32 * 72];
  const int t = threadIdx.x, l = t & 63, wv = t >> 6;
  const int p = blockIdx.x * 4 + wv;   // b*12 + h
  const int b = p / 12, h = p - b * 12;
  const int w = b & 63;
  const size_t base = (size_t)p * (49 * 32);
  const int c = l & 31, b5 = l >> 5;
  bf16* vl = Vl[wv];

  // zero pad keys 48..63 (key 48 re-written by staging below)
  {
    bf16x4 z = {};
    for (int i = l; i < 128; i += 64) {
      int d = i >> 2, kq = 48 + (i & 3) * 4;
      *reinterpret_cast<bf16x4*>(&vl[d * 72 + kq]) = z;
    }
  }
  // stage V transposed: vl[d*72 + key] = V[key*32 + d]
  for (int i = l; i < 392; i += 64) {
    int key = i >> 3, dc = (i & 7) * 4;
    bf16x4 vv = *reinterpret_cast<const bf16x4*>(&V[base + key * 32 + dc]);
#pragma unroll
    for (int j = 0; j < 4; ++j) vl[(dc + j) * 72 + key] = vv[j];
  }

  // K/Q fragments: lane holds X[row = f*32 + c][d = kd*16 + b5*8 + j], rows clamped to 48
  bf16x8 kf[2][2], qf[2][2];
#pragma unroll
  for (int f = 0; f < 2; ++f) {
    int row = f * 32 + c; if (row > 48) row = 48;
#pragma unroll
    for (int kd = 0; kd < 2; ++kd) {
      kf[f][kd] = *reinterpret_cast<const bf16x8*>(&K[base + row * 32 + kd * 16 + b5 * 8]);
      qf[f][kd] = *reinterpret_cast<const bf16x8*>(&Q[base + row * 32 + kd * 16 + b5 * 8]);
    }
  }

  const float scale = 0.17677669529663689f;   // 32^-0.5
  const float* bT = biasT + h * 2401;
  const float* mT = maskT + w * 2401;
  const int qq = /*fn*32 +*/ c;   // query column base; fn added in loop

#pragma unroll
  for (int fn = 0; fn < 2; ++fn) {
    // QK^T: S[key][q], C layout: col=lane&31=q, row=(r&3)+8*(r>>2)+4*b5=key
    f32x16 s0 = {}, s1 = {};
    s0 = MFMA32(kf[0][0], qf[fn][0], s0);
    s0 = MFMA32(kf[0][1], qf[fn][1], s0);
    s1 = MFMA32(kf[1][0], qf[fn][0], s1);
    s1 = MFMA32(kf[1][1], qf[fn][1], s1);

    int q = fn * 32 + qq;
    int qc = q > 48 ? 48 : q;     // clamp for garbage columns (discarded at store)

    float vals[32];
    float vmax = -1e30f;
#pragma unroll
    for (int fm = 0; fm < 2; ++fm) {
#pragma unroll
      for (int r = 0; r < 16; ++r) {
        int kb = fm * 32 + (r & 3) + 8 * (r >> 2);  // key = kb + 4*b5
        int key = kb + 4 * b5;
        float sv = fm ? s1[r] : s0[r];
        float v;
        if (key < 49) {
          float cm = bT[key * 49 + qc] + mT[key * 49 + qc];
          v = fmaf(sv, scale, cm);
        } else {
          v = -1e30f;
        }
        vals[fm * 16 + r] = v;
        vmax = fmaxf(vmax, v);
      }
    }
    vmax = fmaxf(vmax, __shfl_xor(vmax, 32));
    float sum = 0.f;
#pragma unroll
    for (int i = 0; i < 32; ++i) {
      float e = __expf(vals[i] - vmax);
      vals[i] = e;
      sum += e;
    }
    sum += __shfl_xor(sum, 32);
    float inv = 1.f / sum;

    // PV: O[q][d] = P * V. Build A-frag (row=q=c, k=key) from vals via pack+permlane32_swap.
    f32x16 o = {};
#pragma unroll
    for (int kk = 0; kk < 4; ++kk) {
      int ib = (kk >> 1) * 16 + 8 * (kk & 1);   // vals base for this 16-key fragment
      union { bf16 hh[2]; u32 u; } cv;
      u32 A0, A1, B0, B1;
      cv.hh[0] = (bf16)(vals[ib + 0] * inv); cv.hh[1] = (bf16)(vals[ib + 1] * inv); A0 = cv.u;
      cv.hh[0] = (bf16)(vals[ib + 2] * inv); cv.hh[1] = (bf16)(vals[ib + 3] * inv); A1 = cv.u;
      cv.hh[0] = (bf16)(vals[ib + 4] * inv); cv.hh[1] = (bf16)(vals[ib + 5] * inv); B0 = cv.u;
      cv.hh[0] = (bf16)(vals[ib + 6] * inv); cv.hh[1] = (bf16)(vals[ib + 7] * inv); B1 = cv.u;
      i32x2 sw0 = __builtin_amdgcn_permlane32_swap((int)A0, (int)B0, false, false);
      i32x2 sw1 = __builtin_amdgcn_permlane32_swap((int)A1, (int)B1, false, false);
      union { u32 d[4]; bf16x8 v8; } pa;
      pa.d[0] = (u32)sw0[0]; pa.d[1] = (u32)sw1[0];   // j0..3  (from lane (c,0))
      pa.d[2] = (u32)sw0[1]; pa.d[3] = (u32)sw1[1];   // j4..7  (from lane (c,1))
      bf16x8 vf = *reinterpret_cast<const bf16x8*>(&vl[c * 72 + kk * 16 + b5 * 8]);
      o = MFMA32(pa.v8, vf, o);
    }

    // store O: row q = fn*32 + (r&3)+8*(r>>2)+4*b5, col d = c
#pragma unroll
    for (int r = 0; r < 16; ++r) {
      int qrow = fn * 32 + (r & 3) + 8 * (r >> 2) + 4 * b5;
      if (qrow < 49)
        H[((size_t)b * 49 + qrow) * 384 + h * 32 + c] = (bf16)o[r];
    }
  }
}

extern "C" void kernel_launch(void* const* d_in, const int* in_sizes, int n_in,
                              void* d_out, int out_size, void* d_ws, size_t ws_size,
                              hipStream_t stream) {
  const float* x     = (const float*)d_in[0];
  const float* mask  = (const float*)d_in[1];
  const float* qkvw  = (const float*)d_in[2];
  const float* qkvb  = (const float*)d_in[3];
  const float* btab  = (const float*)d_in[4];
  const float* projw = (const float*)d_in[5];
  const float* projb = (const float*)d_in[6];
  const int*   rel   = (const int*)d_in[7];
  float* out = (float*)d_out;

  const size_t NELEM = (size_t)MROWS * DIMC;  // 77,070,336
  char* ws = (char*)d_ws;
  // ws layout (bytes):
  //   xb/hidden [0, 154140672)
  //   v         [154140672, 308281344)
  //   biasT     [308281344, +115456)
  //   wqkv      [308396800, +884736)   <- maskT (614656 B) reuses this AFTER gemm0
  //   wproj     [309281536, +294912)
  bf16*  xb    = (bf16*)ws;
  bf16*  vb    = (bf16*)(ws + 154140672);
  float* biasT = (float*)(ws + 308281344);
  bf16*  wqkv  = (bf16*)(ws + 308396800);
  float* maskT = (float*)(ws + 308396800);   // aliases wqkv; written after gemm0
  bf16*  wproj = (bf16*)(ws + 309281536);
  // q,k live in d_out as scratch (exactly 2 * 154,140,672 B); proj fully overwrites it
  bf16* qb = (bf16*)d_out;
  bf16* kb = qb + NELEM;

  k_convert<<<2048, 256, 0, stream>>>((const float4*)x, (bf16x4*)xb, (int)(NELEM / 4));
  k_convert<<<432, 256, 0, stream>>>((const float4*)qkvw, (bf16x4*)wqkv, 3 * DIMC * DIMC / 4);
  k_convert<<<144, 256, 0, stream>>>((const float4*)projw, (bf16x4*)wproj, DIMC * DIMC / 4);
  k_biasT<<<(NHEADS * NTOK * NTOK + 255) / 256, 256, 0, stream>>>(btab, rel, biasT);

  k_gemm<0><<<dim3(MROWS / 128, 1152 / 128), 256, 0, stream>>>(xb, wqkv, qkvb, qb, kb, vb, nullptr);
  k_maskT<<<(64 * NTOK * NTOK + 255) / 256, 256, 0, stream>>>(mask, maskT);
  k_attn<<<(NWINB * NHEADS) / 4, 256, 0, stream>>>(qb, kb, vb, biasT, maskT, xb);
  k_gemm<1><<<dim3(MROWS / 128, 384 / 128), 256, 0, stream>>>(xb, wproj, projb, nullptr, nullptr, nullptr, out);
}